// Round 13
// baseline (1523.958 us; speedup 1.0000x reference)
//
#include <hip/hip_runtime.h>
#include <math.h>
#include <float.h>

#define DIM 256
// Tie policy (verified PASS R6-R11 — do not change):
#define EPS_TIE 1e-4
#define PREFER_LOWER 1
// Flag margins for the bf16-single fast pass (score err std ~0.05):
#define MARGIN_MERGE 0.75f
#define MARGIN_HALF  0.30f
#define MARGIN_FALLBACK 0.125f

typedef __attribute__((ext_vector_type(8))) short short8;   // 8 bf16 = 4 VGPR
typedef __attribute__((ext_vector_type(4))) float f32x4;

__device__ __forceinline__ unsigned short f32_to_bf16_rne(float f) {
    unsigned int u = __float_as_uint(f);
    u += 0x7fffu + ((u >> 16) & 1u);
    return (unsigned short)(u >> 16);
}
__device__ __forceinline__ void nt_store4(float* p, f32x4 v) {
    __builtin_nontemporal_store(v, (f32x4*)p);
}

// |e_j|^2 (fast pass only, approx ok); one wave per codebook row
__global__ void esq_kernel(const float* __restrict__ embed, float* __restrict__ esq) {
    const int j = blockIdx.x;
    const int lane = threadIdx.x;  // 64
    float4 v = *reinterpret_cast<const float4*>(embed + (size_t)j * DIM + lane * 4);
    float s = v.x * v.x + v.y * v.y + v.z * v.z + v.w * v.w;
#pragma unroll
    for (int m = 32; m >= 1; m >>= 1) s += __shfl_xor(s, m, 64);
    if (lane == 0) esq[j] = s;
}

// embed -> fragment-major bf16 (B operand of mfma_f32_16x16x32_bf16).
// Block b = ct*8 + s. Lane l: col = ct*16 + (l&15), k = s*32 + (l>>4)*8 + i.
__global__ void efrag_kernel(const float* __restrict__ embed,
                             unsigned short* __restrict__ ehi) {
    const int b = blockIdx.x;          // 0..511
    const int l = threadIdx.x;         // 0..63
    const int ct = b >> 3, s = b & 7;
    const int col = ct * 16 + (l & 15);
    const int kb  = s * 32 + (l >> 4) * 8;
    const float* src = embed + (size_t)col * DIM + kb;
    float4 v0 = *reinterpret_cast<const float4*>(src);
    float4 v1 = *reinterpret_cast<const float4*>(src + 4);
    float vv[8] = {v0.x, v0.y, v0.z, v0.w, v1.x, v1.y, v1.z, v1.w};
    size_t base = ((size_t)b * 64 + l) * 8;
#pragma unroll
    for (int i = 0; i < 8; ++i) ehi[base + i] = f32_to_bf16_rne(vv[i]);
}

// ---- fast pass: 8 waves; wave owns 64 cols (e-frags in REGISTERS, 128 VGPR);
// block covers 512 rows x 512 cols (half). x staged in LDS as A-fragments,
// each ds_read feeds 4 MFMAs. Emits per-row (v1, v2, i1) partials.
__global__ __launch_bounds__(512, 2) void
vq_fast_kernel(const float* __restrict__ x, const unsigned short* __restrict__ ehi,
               const float* __restrict__ esq, f32x4* __restrict__ part, int N) {
    __shared__ unsigned short xfrag[4][8][512];   // [rt][s][64 lanes x 8] = 32 KB
    __shared__ float wv1[8][64], wv2[8][64];
    __shared__ int   wi1[8][64];
    __shared__ float esq_l[512];

    const int t  = threadIdx.x;
    const int w  = t >> 6;        // wave 0..7: owns cols cbase + w*64 ..+63
    const int l  = t & 63;
    const int ar = l & 15;
    const int ag = l >> 4;
    const int half  = blockIdx.x & 1;
    const int rbase = (blockIdx.x >> 1) * 512;
    const int cbase = half * 512;

    for (int i = t; i < 512; i += 512) esq_l[i] = esq[cbase + i];

    // resident e fragments: 4 ct x 8 s (proven efrag layout)
    short8 eh[4][8];
#pragma unroll
    for (int ct = 0; ct < 4; ++ct)
#pragma unroll
        for (int s = 0; s < 8; ++s) {
            const int ctg = half * 32 + w * 4 + ct;
            eh[ct][s] = *reinterpret_cast<const short8*>(
                ehi + (((size_t)ctg * 8 + s) * 64 + l) * 8);
        }

    for (int tile = 0; tile < 8; ++tile) {
        const int trow0 = rbase + tile * 64;
        __syncthreads();                      // previous tile fully consumed
        // stage: wave w writes frags f = w*4..w*4+3  (rt = f>>3, s = f&7)
#pragma unroll
        for (int i = 0; i < 4; ++i) {
            const int f = w * 4 + i, rt = f >> 3, s = f & 7;
            const float* src = x + (size_t)(trow0 + rt * 16 + ar) * DIM + s * 32 + ag * 8;
            float4 v0 = *reinterpret_cast<const float4*>(src);
            float4 v1 = *reinterpret_cast<const float4*>(src + 4);
            float vv[8] = {v0.x, v0.y, v0.z, v0.w, v1.x, v1.y, v1.z, v1.w};
            short8 hv;
#pragma unroll
            for (int j = 0; j < 8; ++j) hv[j] = (short)f32_to_bf16_rne(vv[j]);
            *reinterpret_cast<short8*>(&xfrag[rt][s][l * 8]) = hv;
        }
        __syncthreads();

        f32x4 acc[4][4];
#pragma unroll
        for (int rt = 0; rt < 4; ++rt)
#pragma unroll
            for (int ct = 0; ct < 4; ++ct) acc[rt][ct] = (f32x4)0.0f;

#pragma unroll
        for (int s = 0; s < 8; ++s)
#pragma unroll
            for (int rt = 0; rt < 4; ++rt) {
                short8 xa = *reinterpret_cast<const short8*>(&xfrag[rt][s][l * 8]);
#pragma unroll
                for (int ct = 0; ct < 4; ++ct)
                    acc[rt][ct] = __builtin_amdgcn_mfma_f32_16x16x32_bf16(
                        xa, eh[ct][s], acc[rt][ct], 0, 0, 0);
            }

        // finalize: per (rt, r) one row; per-lane top-2 over 4 ct, butterfly over ar
#pragma unroll
        for (int rt = 0; rt < 4; ++rt)
#pragma unroll
            for (int r = 0; r < 4; ++r) {
                float v1 = INFINITY, v2 = INFINITY; int i1 = 0;
#pragma unroll
                for (int ct = 0; ct < 4; ++ct) {
                    const int col = cbase + w * 64 + ct * 16 + ar;
                    float sc = fmaf(-2.0f, acc[rt][ct][r], esq_l[w * 64 + ct * 16 + ar]);
                    if (sc < v1) { v2 = v1; v1 = sc; i1 = col; }
                    else if (sc < v2) v2 = sc;
                }
#pragma unroll
                for (int m = 1; m < 16; m <<= 1) {
                    float ov1 = __shfl_xor(v1, m, 64);
                    int   oi1 = __shfl_xor(i1, m, 64);
                    float ov2 = __shfl_xor(v2, m, 64);
                    float nv2 = fminf(fmaxf(v1, ov1), fminf(v2, ov2));
                    if (ov1 < v1 || (ov1 == v1 && oi1 < i1)) { v1 = ov1; i1 = oi1; }
                    v2 = nv2;
                }
                if (ar == 0) {
                    const int rl = rt * 16 + ag * 4 + r;
                    wv1[w][rl] = v1; wi1[w][rl] = i1; wv2[w][rl] = v2;
                }
            }
        __syncthreads();
        if (t < 64) {   // cross-wave merge (waves ascend = cols ascend) -> partial
            float v1 = wv1[0][t]; int i1 = wi1[0][t]; float v2 = wv2[0][t];
#pragma unroll
            for (int ww = 1; ww < 8; ++ww) {
                float ov1 = wv1[ww][t]; int oi1 = wi1[ww][t]; float ov2 = wv2[ww][t];
                float nv2 = fminf(fmaxf(v1, ov1), fminf(v2, ov2));
                if (ov1 < v1 || (ov1 == v1 && oi1 < i1)) { v1 = ov1; i1 = oi1; }
                v2 = nv2;
            }
            f32x4 p; p[0] = v1; p[1] = v2; p[2] = __int_as_float(i1); p[3] = 0.0f;
            part[(size_t)(trow0 + t) * 2 + half] = p;
        }
        // next loop-top barrier orders wv reuse
    }
}

// ---- merge halves + outputs + exact (fp64) refine + tie policy (R6-verified) ----
__global__ __launch_bounds__(256) void
vq_merge_kernel(const float* __restrict__ x, const float* __restrict__ embed,
                const f32x4* __restrict__ part, float* __restrict__ out, int N, int K) {
    __shared__ int    rowidx[64];
    __shared__ int    flr[64];
    __shared__ int    nflag;
    __shared__ double rv1[256], rv2[256];
    __shared__ int    ri1[256], ri2[256];
    __shared__ float  xrow[DIM];

    const int t = threadIdx.x;
    const int w = t >> 6, l = t & 63;
    const int row0 = blockIdx.x * 64;
    if (t == 0) nflag = 0;
    __syncthreads();

    if (t < 64) {
        const int row = row0 + t;
        f32x4 a = part[(size_t)row * 2 + 0];
        f32x4 b = part[(size_t)row * 2 + 1];
        float av1 = a[0], av2 = a[1]; int ai1 = __float_as_int(a[2]);
        float bv1 = b[0], bv2 = b[1]; int bi1 = __float_as_int(b[2]);
        float v1; int i1; float v2;
        if (bv1 < av1) { v1 = bv1; i1 = bi1; v2 = fminf(av1, bv2); }
        else           { v1 = av1; i1 = ai1; v2 = fminf(bv1, av2); }  // tie: half0 (lower cols)
        rowidx[t] = i1;
        bool flag = (v2 - v1 < MARGIN_MERGE) ||
                    (av2 - av1 < MARGIN_HALF) || (bv2 - bv1 < MARGIN_HALF);
        if (flag) { int p = atomicAdd(&nflag, 1); flr[p] = t; }
    }
    __syncthreads();

    const size_t IOFF = (size_t)N * DIM;
    const size_t ROFF = IOFF + (size_t)N;
    // outputs: wave w writes rows it*4+w; lane l covers d = l*4..l*4+3
#pragma unroll
    for (int it = 0; it < 16; ++it) {
        const int rl  = it * 4 + w;
        const int row = row0 + rl;
        const int idx = rowidx[rl];
        if (l == 0) out[IOFF + row] = (float)idx;
        f32x4 e  = *reinterpret_cast<const f32x4*>(embed + (size_t)idx * DIM + l * 4);
        f32x4 xv = *reinterpret_cast<const f32x4*>(x + (size_t)row * DIM + l * 4);
        nt_store4(out + (size_t)row * DIM + l * 4, e);
        nt_store4(out + ROFF + (size_t)row * DIM + l * 4, e - xv);
    }

    // exact fp64 top-2 refinement + tie policy (verbatim R6)
    __syncthreads();
    const int nf = nflag;
    for (int f = 0; f < nf; ++f) {
        const int row = row0 + flr[f];
        if (t < 64) {
            float4 v = *reinterpret_cast<const float4*>(x + (size_t)row * DIM + t * 4);
            xrow[t * 4 + 0] = v.x; xrow[t * 4 + 1] = v.y;
            xrow[t * 4 + 2] = v.z; xrow[t * 4 + 3] = v.w;
        }
        __syncthreads();

        double v1 = DBL_MAX, v2 = DBL_MAX; int i1 = 0x7fffffff, i2 = 0x7fffffff;
#pragma unroll
        for (int jj = 0; jj < 4; ++jj) {
            const int j = t * 4 + jj;
            const float* e = embed + (size_t)j * DIM;
            double xe = 0.0, ee = 0.0;
            for (int kg = 0; kg < DIM / 4; ++kg) {
                float4 ev = *reinterpret_cast<const float4*>(e + kg * 4);
                double e0 = ev.x, e1 = ev.y, e2 = ev.z, e3 = ev.w;
                xe += e0 * (double)xrow[kg * 4 + 0] + e1 * (double)xrow[kg * 4 + 1]
                    + e2 * (double)xrow[kg * 4 + 2] + e3 * (double)xrow[kg * 4 + 3];
                ee += e0 * e0 + e1 * e1 + e2 * e2 + e3 * e3;
            }
            double d = ee - 2.0 * xe;            // shift-invariant score
            if (d < v1 || (d == v1 && j < i1)) { v2 = v1; i2 = i1; v1 = d; i1 = j; }
            else if (d < v2 || (d == v2 && j < i2)) { v2 = d; i2 = j; }
        }
        rv1[t] = v1; ri1[t] = i1; rv2[t] = v2; ri2[t] = i2;
        __syncthreads();
        for (int s = 128; s > 0; s >>= 1) {
            if (t < s) {
                double a1 = rv1[t],     a2 = rv2[t];     int k1 = ri1[t],     k2 = ri2[t];
                double b1 = rv1[t + s], b2 = rv2[t + s]; int j1 = ri1[t + s], j2 = ri2[t + s];
                double w1, w2; int m1, m2;
                bool bfirst = (b1 < a1) || (b1 == a1 && j1 < k1);
                if (bfirst) {
                    w1 = b1; m1 = j1;
                    if (a1 < b2 || (a1 == b2 && k1 < j2)) { w2 = a1; m2 = k1; }
                    else                                   { w2 = b2; m2 = j2; }
                } else {
                    w1 = a1; m1 = k1;
                    if (b1 < a2 || (b1 == a2 && j1 < k2)) { w2 = b1; m2 = j1; }
                    else                                   { w2 = a2; m2 = k2; }
                }
                rv1[t] = w1; ri1[t] = m1; rv2[t] = w2; ri2[t] = m2;
            }
            __syncthreads();
        }
        int idx = ri1[0];
        {
            const double gap = rv2[0] - rv1[0];
#if PREFER_LOWER
            if (gap < EPS_TIE && ri2[0] < ri1[0]) idx = ri2[0];
#else
            if (gap < EPS_TIE && ri2[0] > ri1[0]) idx = ri2[0];
#endif
        }
        if (t == 0) out[IOFF + row] = (float)idx;
        if (t < 64) {
            int d0 = t * 4;
            float4 e  = *reinterpret_cast<const float4*>(embed + (size_t)idx * DIM + d0);
            float4 xv = *reinterpret_cast<const float4*>(x + (size_t)row * DIM + d0);
            *reinterpret_cast<float4*>(out + (size_t)row * DIM + d0) = e;
            float4 rr = make_float4(e.x - xv.x, e.y - xv.y, e.z - xv.z, e.w - xv.w);
            *reinterpret_cast<float4*>(out + ROFF + (size_t)row * DIM + d0) = rr;
        }
        __syncthreads();
    }
}

// ================= fallback: R6-verified VALU path (used if ws too small) ====
#define BM 64
#define BN 64
#define DK 64
__global__ __launch_bounds__(256, 4)
void vq_argmin_kernel(const float* __restrict__ x, const float* __restrict__ embed,
                      const float* __restrict__ esq, float* __restrict__ out,
                      int N, int K) {
    __shared__ float xs[DK][BM];
    __shared__ float es[DK][BN];
    __shared__ double rv1[256], rv2[256];
    __shared__ int    ri1[256], ri2[256];
    __shared__ float  xrow[DIM];
    __shared__ int    flr[BM];
    __shared__ int    nflag;

    const int t = threadIdx.x;
    const int tx = t & 15, ty = t >> 4;
    const int row0 = blockIdx.x * BM;
    if (t == 0) nflag = 0;

    float minv[4], min2v[4]; int mini[4];
#pragma unroll
    for (int r = 0; r < 4; ++r) { minv[r] = INFINITY; min2v[r] = INFINITY; mini[r] = 0; }

    for (int jc = 0; jc < K / BN; ++jc) {
        float acc[4][4];
#pragma unroll
        for (int r = 0; r < 4; ++r)
#pragma unroll
            for (int c = 0; c < 4; ++c) acc[r][c] = 0.0f;
        for (int dc = 0; dc < DIM / DK; ++dc) {
            __syncthreads();
#pragma unroll
            for (int it = 0; it < 4; ++it) {
                int idx = t + 256 * it, r = idx & 63, kg = idx >> 6;
                float4 v = *reinterpret_cast<const float4*>(
                    x + (size_t)(row0 + r) * DIM + dc * DK + kg * 4);
                xs[kg*4+0][r] = v.x; xs[kg*4+1][r] = v.y; xs[kg*4+2][r] = v.z; xs[kg*4+3][r] = v.w;
            }
#pragma unroll
            for (int it = 0; it < 4; ++it) {
                int idx = t + 256 * it, c = idx & 63, kg = idx >> 6;
                float4 v = *reinterpret_cast<const float4*>(
                    embed + (size_t)(jc * BN + c) * DIM + dc * DK + kg * 4);
                es[kg*4+0][c] = v.x; es[kg*4+1][c] = v.y; es[kg*4+2][c] = v.z; es[kg*4+3][c] = v.w;
            }
            __syncthreads();
#pragma unroll
            for (int k = 0; k < DK; ++k) {
                float4 a = *reinterpret_cast<const float4*>(&xs[k][ty * 4]);
                float4 b = *reinterpret_cast<const float4*>(&es[k][tx * 4]);
                float arr[4] = {a.x, a.y, a.z, a.w}, bc[4] = {b.x, b.y, b.z, b.w};
#pragma unroll
                for (int r = 0; r < 4; ++r)
#pragma unroll
                    for (int c = 0; c < 4; ++c) acc[r][c] = fmaf(arr[r], bc[c], acc[r][c]);
            }
        }
        float4 eq = *reinterpret_cast<const float4*>(esq + jc * BN + tx * 4);
        float eqa[4] = {eq.x, eq.y, eq.z, eq.w};
#pragma unroll
        for (int c = 0; c < 4; ++c) {
            int j = jc * BN + tx * 4 + c;
#pragma unroll
            for (int r = 0; r < 4; ++r) {
                float s = fmaf(-2.0f, acc[r][c], eqa[c]);
                if (s < minv[r]) { min2v[r] = minv[r]; minv[r] = s; mini[r] = j; }
                else if (s < min2v[r]) { min2v[r] = s; }
            }
        }
    }
#pragma unroll
    for (int r = 0; r < 4; ++r) {
        float v1 = minv[r]; int i1 = mini[r]; float v2 = min2v[r];
#pragma unroll
        for (int m = 1; m < 16; m <<= 1) {
            float ov1 = __shfl_xor(v1, m, 64); int oi1 = __shfl_xor(i1, m, 64);
            float ov2 = __shfl_xor(v2, m, 64);
            float nv2 = fminf(fmaxf(v1, ov1), fminf(v2, ov2));
            if (ov1 < v1 || (ov1 == v1 && oi1 < i1)) { v1 = ov1; i1 = oi1; }
            v2 = nv2;
        }
        minv[r] = v1; mini[r] = i1; min2v[r] = v2;
    }
    const size_t IOFF = (size_t)N * DIM, ROFF = IOFF + (size_t)N;
#pragma unroll
    for (int r = 0; r < 4; ++r) {
        int row = row0 + ty * 4 + r, idx = mini[r];
        if (tx == 0) {
            out[IOFF + row] = (float)idx;
            if (min2v[r] - minv[r] < MARGIN_FALLBACK) { int p = atomicAdd(&nflag, 1); flr[p] = ty * 4 + r; }
        }
#pragma unroll
        for (int g = 0; g < 4; ++g) {
            int d0 = tx * 16 + g * 4;
            float4 e  = *reinterpret_cast<const float4*>(embed + (size_t)idx * DIM + d0);
            float4 xv = *reinterpret_cast<const float4*>(x + (size_t)row * DIM + d0);
            *reinterpret_cast<float4*>(out + (size_t)row * DIM + d0) = e;
            float4 rr = make_float4(e.x - xv.x, e.y - xv.y, e.z - xv.z, e.w - xv.w);
            *reinterpret_cast<float4*>(out + ROFF + (size_t)row * DIM + d0) = rr;
        }
    }
    __syncthreads();
    const int nf = nflag;
    for (int f = 0; f < nf; ++f) {
        const int row = row0 + flr[f];
        if (t < 64) {
            float4 v = *reinterpret_cast<const float4*>(x + (size_t)row * DIM + t * 4);
            xrow[t*4+0] = v.x; xrow[t*4+1] = v.y; xrow[t*4+2] = v.z; xrow[t*4+3] = v.w;
        }
        __syncthreads();
        double v1 = DBL_MAX, v2 = DBL_MAX; int i1 = 0x7fffffff, i2 = 0x7fffffff;
#pragma unroll
        for (int jj = 0; jj < 4; ++jj) {
            const int j = t * 4 + jj;
            const float* e = embed + (size_t)j * DIM;
            double xe = 0.0, ee = 0.0;
            for (int kg = 0; kg < DIM / 4; ++kg) {
                float4 ev = *reinterpret_cast<const float4*>(e + kg * 4);
                double e0 = ev.x, e1 = ev.y, e2 = ev.z, e3 = ev.w;
                xe += e0*(double)xrow[kg*4+0] + e1*(double)xrow[kg*4+1]
                    + e2*(double)xrow[kg*4+2] + e3*(double)xrow[kg*4+3];
                ee += e0*e0 + e1*e1 + e2*e2 + e3*e3;
            }
            double d = ee - 2.0 * xe;
            if (d < v1 || (d == v1 && j < i1)) { v2 = v1; i2 = i1; v1 = d; i1 = j; }
            else if (d < v2 || (d == v2 && j < i2)) { v2 = d; i2 = j; }
        }
        rv1[t] = v1; ri1[t] = i1; rv2[t] = v2; ri2[t] = i2;
        __syncthreads();
        for (int s = 128; s > 0; s >>= 1) {
            if (t < s) {
                double a1 = rv1[t], a2 = rv2[t]; int k1 = ri1[t], k2 = ri2[t];
                double b1 = rv1[t+s], b2 = rv2[t+s]; int j1 = ri1[t+s], j2 = ri2[t+s];
                double w1, w2; int m1, m2;
                bool bfirst = (b1 < a1) || (b1 == a1 && j1 < k1);
                if (bfirst) { w1 = b1; m1 = j1;
                    if (a1 < b2 || (a1 == b2 && k1 < j2)) { w2 = a1; m2 = k1; } else { w2 = b2; m2 = j2; }
                } else { w1 = a1; m1 = k1;
                    if (b1 < a2 || (b1 == a2 && j1 < k2)) { w2 = b1; m2 = j1; } else { w2 = a2; m2 = k2; }
                }
                rv1[t] = w1; ri1[t] = m1; rv2[t] = w2; ri2[t] = m2;
            }
            __syncthreads();
        }
        int idx = ri1[0];
        const double gap = rv2[0] - rv1[0];
#if PREFER_LOWER
        if (gap < EPS_TIE && ri2[0] < ri1[0]) idx = ri2[0];
#else
        if (gap < EPS_TIE && ri2[0] > ri1[0]) idx = ri2[0];
#endif
        if (t == 0) out[IOFF + row] = (float)idx;
        if (t < 64) {
            int d0 = t * 4;
            float4 e  = *reinterpret_cast<const float4*>(embed + (size_t)idx * DIM + d0);
            float4 xv = *reinterpret_cast<const float4*>(x + (size_t)row * DIM + d0);
            *reinterpret_cast<float4*>(out + (size_t)row * DIM + d0) = e;
            float4 rr = make_float4(e.x - xv.x, e.y - xv.y, e.z - xv.z, e.w - xv.w);
            *reinterpret_cast<float4*>(out + ROFF + (size_t)row * DIM + d0) = rr;
        }
        __syncthreads();
    }
}

extern "C" void kernel_launch(void* const* d_in, const int* in_sizes, int n_in,
                              void* d_out, int out_size, void* d_ws, size_t ws_size,
                              hipStream_t stream) {
    const float* x     = (const float*)d_in[0];
    const float* embed = (const float*)d_in[1];
    float* out = (float*)d_out;
    const int N = in_sizes[0] / DIM;   // 65536
    const int K = in_sizes[1] / DIM;   // 1024

    // ws: [0,4KB) esq | [4KB,+512KB) ehi | [aligned 16, 2MB) partials
    float* esq = (float*)d_ws;
    unsigned short* ehi = (unsigned short*)((char*)d_ws + 4096);
    f32x4* part = (f32x4*)((char*)d_ws + 4096 + 524288);
    const size_t need = 4096 + 524288 + (size_t)N * 2 * 16;

    esq_kernel<<<K, 64, 0, stream>>>(embed, esq);
    if (ws_size >= need) {
        efrag_kernel<<<(K / 16) * 8, 64, 0, stream>>>(embed, ehi);
        vq_fast_kernel<<<(N / 512) * 2, 512, 0, stream>>>(x, ehi, esq, part, N);
        vq_merge_kernel<<<N / 64, 256, 0, stream>>>(x, embed, part, out, N, K);
    } else {
        vq_argmin_kernel<<<N / BM, 256, 0, stream>>>(x, embed, esq, out, N, K);
    }
}

// Round 14
// 1354.231 us; speedup vs baseline: 1.1253x; 1.1253x over previous
//
#include <hip/hip_runtime.h>
#include <math.h>
#include <float.h>

#define DIM 256
// Tie policy (verified PASS R6-R13 — do not change):
#define EPS_TIE 1e-4
#define PREFER_LOWER 1
// Flag margins for the bf16-single fast pass (verified absmax 0 in R13):
#define MARGIN_MERGE 0.75f
#define MARGIN_HALF  0.30f
#define MARGIN_FALLBACK 0.125f

typedef __attribute__((ext_vector_type(8))) short short8;   // 8 bf16 = 4 VGPR
typedef __attribute__((ext_vector_type(4))) float f32x4;

__device__ __forceinline__ unsigned short f32_to_bf16_rne(float f) {
    unsigned int u = __float_as_uint(f);
    u += 0x7fffu + ((u >> 16) & 1u);
    return (unsigned short)(u >> 16);
}
__device__ __forceinline__ void nt_store4(float* p, f32x4 v) {
    __builtin_nontemporal_store(v, (f32x4*)p);
}

// |e_j|^2 (fast pass only, approx ok); one wave per codebook row
__global__ void esq_kernel(const float* __restrict__ embed, float* __restrict__ esq) {
    const int j = blockIdx.x;
    const int lane = threadIdx.x;  // 64
    float4 v = *reinterpret_cast<const float4*>(embed + (size_t)j * DIM + lane * 4);
    float s = v.x * v.x + v.y * v.y + v.z * v.z + v.w * v.w;
#pragma unroll
    for (int m = 32; m >= 1; m >>= 1) s += __shfl_xor(s, m, 64);
    if (lane == 0) esq[j] = s;
}

// embed -> fragment-major bf16 (B operand of mfma_f32_16x16x32_bf16).
// Block b = ct*8 + s. Lane l: col = ct*16 + (l&15), k = s*32 + (l>>4)*8 + i.
__global__ void efrag_kernel(const float* __restrict__ embed,
                             unsigned short* __restrict__ ehi) {
    const int b = blockIdx.x;          // 0..511
    const int l = threadIdx.x;         // 0..63
    const int ct = b >> 3, s = b & 7;
    const int col = ct * 16 + (l & 15);
    const int kb  = s * 32 + (l >> 4) * 8;
    const float* src = embed + (size_t)col * DIM + kb;
    float4 v0 = *reinterpret_cast<const float4*>(src);
    float4 v1 = *reinterpret_cast<const float4*>(src + 4);
    float vv[8] = {v0.x, v0.y, v0.z, v0.w, v1.x, v1.y, v1.z, v1.w};
    size_t base = ((size_t)b * 64 + l) * 8;
#pragma unroll
    for (int i = 0; i < 8; ++i) ehi[base + i] = f32_to_bf16_rne(vv[i]);
}

// ---- fast pass (VERIFIED R13): 8 waves; wave owns 64 cols (e-frags in regs);
// block covers 512 rows x 512 cols (half). x staged in LDS as A-fragments.
// Emits per-row (v1, v2, i1) partials.
__global__ __launch_bounds__(512, 2) void
vq_fast_kernel(const float* __restrict__ x, const unsigned short* __restrict__ ehi,
               const float* __restrict__ esq, f32x4* __restrict__ part, int N) {
    __shared__ unsigned short xfrag[4][8][512];   // [rt][s][64 lanes x 8] = 32 KB
    __shared__ float wv1[8][64], wv2[8][64];
    __shared__ int   wi1[8][64];
    __shared__ float esq_l[512];

    const int t  = threadIdx.x;
    const int w  = t >> 6;        // wave 0..7: owns cols cbase + w*64 ..+63
    const int l  = t & 63;
    const int ar = l & 15;
    const int ag = l >> 4;
    const int half  = blockIdx.x & 1;
    const int rbase = (blockIdx.x >> 1) * 512;
    const int cbase = half * 512;

    for (int i = t; i < 512; i += 512) esq_l[i] = esq[cbase + i];

    // resident e fragments: 4 ct x 8 s (proven efrag layout)
    short8 eh[4][8];
#pragma unroll
    for (int ct = 0; ct < 4; ++ct)
#pragma unroll
        for (int s = 0; s < 8; ++s) {
            const int ctg = half * 32 + w * 4 + ct;
            eh[ct][s] = *reinterpret_cast<const short8*>(
                ehi + (((size_t)ctg * 8 + s) * 64 + l) * 8);
        }

    for (int tile = 0; tile < 8; ++tile) {
        const int trow0 = rbase + tile * 64;
        __syncthreads();                      // previous tile fully consumed
        // stage: wave w writes frags f = w*4..w*4+3  (rt = f>>3, s = f&7)
#pragma unroll
        for (int i = 0; i < 4; ++i) {
            const int f = w * 4 + i, rt = f >> 3, s = f & 7;
            const float* src = x + (size_t)(trow0 + rt * 16 + ar) * DIM + s * 32 + ag * 8;
            float4 v0 = *reinterpret_cast<const float4*>(src);
            float4 v1 = *reinterpret_cast<const float4*>(src + 4);
            float vv[8] = {v0.x, v0.y, v0.z, v0.w, v1.x, v1.y, v1.z, v1.w};
            short8 hv;
#pragma unroll
            for (int j = 0; j < 8; ++j) hv[j] = (short)f32_to_bf16_rne(vv[j]);
            *reinterpret_cast<short8*>(&xfrag[rt][s][l * 8]) = hv;
        }
        __syncthreads();

        f32x4 acc[4][4];
#pragma unroll
        for (int rt = 0; rt < 4; ++rt)
#pragma unroll
            for (int ct = 0; ct < 4; ++ct) acc[rt][ct] = (f32x4)0.0f;

#pragma unroll
        for (int s = 0; s < 8; ++s)
#pragma unroll
            for (int rt = 0; rt < 4; ++rt) {
                short8 xa = *reinterpret_cast<const short8*>(&xfrag[rt][s][l * 8]);
#pragma unroll
                for (int ct = 0; ct < 4; ++ct)
                    acc[rt][ct] = __builtin_amdgcn_mfma_f32_16x16x32_bf16(
                        xa, eh[ct][s], acc[rt][ct], 0, 0, 0);
            }

        // finalize: per (rt, r) one row; per-lane top-2 over 4 ct, butterfly over ar
#pragma unroll
        for (int rt = 0; rt < 4; ++rt)
#pragma unroll
            for (int r = 0; r < 4; ++r) {
                float v1 = INFINITY, v2 = INFINITY; int i1 = 0;
#pragma unroll
                for (int ct = 0; ct < 4; ++ct) {
                    const int col = cbase + w * 64 + ct * 16 + ar;
                    float sc = fmaf(-2.0f, acc[rt][ct][r], esq_l[w * 64 + ct * 16 + ar]);
                    if (sc < v1) { v2 = v1; v1 = sc; i1 = col; }
                    else if (sc < v2) v2 = sc;
                }
#pragma unroll
                for (int m = 1; m < 16; m <<= 1) {
                    float ov1 = __shfl_xor(v1, m, 64);
                    int   oi1 = __shfl_xor(i1, m, 64);
                    float ov2 = __shfl_xor(v2, m, 64);
                    float nv2 = fminf(fmaxf(v1, ov1), fminf(v2, ov2));
                    if (ov1 < v1 || (ov1 == v1 && oi1 < i1)) { v1 = ov1; i1 = oi1; }
                    v2 = nv2;
                }
                if (ar == 0) {
                    const int rl = rt * 16 + ag * 4 + r;
                    wv1[w][rl] = v1; wi1[w][rl] = i1; wv2[w][rl] = v2;
                }
            }
        __syncthreads();
        if (t < 64) {   // cross-wave merge (waves ascend = cols ascend) -> partial
            float v1 = wv1[0][t]; int i1 = wi1[0][t]; float v2 = wv2[0][t];
#pragma unroll
            for (int ww = 1; ww < 8; ++ww) {
                float ov1 = wv1[ww][t]; int oi1 = wi1[ww][t]; float ov2 = wv2[ww][t];
                float nv2 = fminf(fmaxf(v1, ov1), fminf(v2, ov2));
                if (ov1 < v1 || (ov1 == v1 && oi1 < i1)) { v1 = ov1; i1 = oi1; }
                v2 = nv2;
            }
            f32x4 p; p[0] = v1; p[1] = v2; p[2] = __int_as_float(i1); p[3] = 0.0f;
            part[(size_t)(trow0 + t) * 2 + half] = p;
        }
        // next loop-top barrier orders wv reuse
    }
}

// ---- merge halves + outputs + exact (fp64) refine + tie policy ----
// Refine rewritten kg-outer / jj-inner (R13 was latency-serialized: dependent
// L2 load per kg in 4 sequential jj loops). Same accumulation order per
// candidate (kg ascending) -> bit-identical fp64 results.
__global__ __launch_bounds__(256) void
vq_merge_kernel(const float* __restrict__ x, const float* __restrict__ embed,
                const f32x4* __restrict__ part, float* __restrict__ out, int N, int K) {
    __shared__ int    rowidx[64];
    __shared__ int    flr[64];
    __shared__ int    nflag;
    __shared__ double rv1[256], rv2[256];
    __shared__ int    ri1[256], ri2[256];
    __shared__ float  xrow[DIM];

    const int t = threadIdx.x;
    const int w = t >> 6, l = t & 63;
    const int row0 = blockIdx.x * 64;
    if (t == 0) nflag = 0;
    __syncthreads();

    if (t < 64) {
        const int row = row0 + t;
        f32x4 a = part[(size_t)row * 2 + 0];
        f32x4 b = part[(size_t)row * 2 + 1];
        float av1 = a[0], av2 = a[1]; int ai1 = __float_as_int(a[2]);
        float bv1 = b[0], bv2 = b[1]; int bi1 = __float_as_int(b[2]);
        float v1; int i1; float v2;
        if (bv1 < av1) { v1 = bv1; i1 = bi1; v2 = fminf(av1, bv2); }
        else           { v1 = av1; i1 = ai1; v2 = fminf(bv1, av2); }  // tie: half0 (lower cols)
        rowidx[t] = i1;
        bool flag = (v2 - v1 < MARGIN_MERGE) ||
                    (av2 - av1 < MARGIN_HALF) || (bv2 - bv1 < MARGIN_HALF);
        if (flag) { int p = atomicAdd(&nflag, 1); flr[p] = t; }
    }
    __syncthreads();

    const size_t IOFF = (size_t)N * DIM;
    const size_t ROFF = IOFF + (size_t)N;
    // outputs: wave w writes rows it*4+w; lane l covers d = l*4..l*4+3
#pragma unroll
    for (int it = 0; it < 16; ++it) {
        const int rl  = it * 4 + w;
        const int row = row0 + rl;
        const int idx = rowidx[rl];
        if (l == 0) out[IOFF + row] = (float)idx;
        f32x4 e  = *reinterpret_cast<const f32x4*>(embed + (size_t)idx * DIM + l * 4);
        f32x4 xv = *reinterpret_cast<const f32x4*>(x + (size_t)row * DIM + l * 4);
        nt_store4(out + (size_t)row * DIM + l * 4, e);
        nt_store4(out + ROFF + (size_t)row * DIM + l * 4, e - xv);
    }

    // exact fp64 top-2 refinement + tie policy (same math; ILP-restructured)
    __syncthreads();
    const int nf = nflag;
    for (int f = 0; f < nf; ++f) {
        const int row = row0 + flr[f];
        if (t < 64) {
            float4 v = *reinterpret_cast<const float4*>(x + (size_t)row * DIM + t * 4);
            xrow[t * 4 + 0] = v.x; xrow[t * 4 + 1] = v.y;
            xrow[t * 4 + 2] = v.z; xrow[t * 4 + 3] = v.w;
        }
        __syncthreads();

        // kg-outer / jj-inner: 4 independent candidate chains, loads pipelined
        double xe[4], ee[4];
#pragma unroll
        for (int jj = 0; jj < 4; ++jj) { xe[jj] = 0.0; ee[jj] = 0.0; }
        const float* ebase = embed + (size_t)(t * 4) * DIM;
#pragma unroll 4
        for (int kg = 0; kg < DIM / 4; ++kg) {
            const double x0 = xrow[kg * 4 + 0], x1 = xrow[kg * 4 + 1];
            const double x2 = xrow[kg * 4 + 2], x3 = xrow[kg * 4 + 3];
#pragma unroll
            for (int jj = 0; jj < 4; ++jj) {
                float4 ev = *reinterpret_cast<const float4*>(ebase + (size_t)jj * DIM + kg * 4);
                double e0 = ev.x, e1 = ev.y, e2 = ev.z, e3 = ev.w;
                xe[jj] += e0 * x0 + e1 * x1 + e2 * x2 + e3 * x3;
                ee[jj] += e0 * e0 + e1 * e1 + e2 * e2 + e3 * e3;
            }
        }
        double v1 = DBL_MAX, v2 = DBL_MAX; int i1 = 0x7fffffff, i2 = 0x7fffffff;
#pragma unroll
        for (int jj = 0; jj < 4; ++jj) {
            const int j = t * 4 + jj;
            double d = ee[jj] - 2.0 * xe[jj];     // shift-invariant score
            if (d < v1 || (d == v1 && j < i1)) { v2 = v1; i2 = i1; v1 = d; i1 = j; }
            else if (d < v2 || (d == v2 && j < i2)) { v2 = d; i2 = j; }
        }
        rv1[t] = v1; ri1[t] = i1; rv2[t] = v2; ri2[t] = i2;
        __syncthreads();
        for (int s = 128; s > 0; s >>= 1) {
            if (t < s) {
                double a1 = rv1[t],     a2 = rv2[t];     int k1 = ri1[t],     k2 = ri2[t];
                double b1 = rv1[t + s], b2 = rv2[t + s]; int j1 = ri1[t + s], j2 = ri2[t + s];
                double w1, w2; int m1, m2;
                bool bfirst = (b1 < a1) || (b1 == a1 && j1 < k1);
                if (bfirst) {
                    w1 = b1; m1 = j1;
                    if (a1 < b2 || (a1 == b2 && k1 < j2)) { w2 = a1; m2 = k1; }
                    else                                   { w2 = b2; m2 = j2; }
                } else {
                    w1 = a1; m1 = k1;
                    if (b1 < a2 || (b1 == a2 && j1 < k2)) { w2 = b1; m2 = j1; }
                    else                                   { w2 = a2; m2 = k2; }
                }
                rv1[t] = w1; ri1[t] = m1; rv2[t] = w2; ri2[t] = m2;
            }
            __syncthreads();
        }
        int idx = ri1[0];
        {
            const double gap = rv2[0] - rv1[0];
#if PREFER_LOWER
            if (gap < EPS_TIE && ri2[0] < ri1[0]) idx = ri2[0];
#else
            if (gap < EPS_TIE && ri2[0] > ri1[0]) idx = ri2[0];
#endif
        }
        if (t == 0) out[IOFF + row] = (float)idx;
        if (t < 64) {
            int d0 = t * 4;
            float4 e  = *reinterpret_cast<const float4*>(embed + (size_t)idx * DIM + d0);
            float4 xv = *reinterpret_cast<const float4*>(x + (size_t)row * DIM + d0);
            *reinterpret_cast<float4*>(out + (size_t)row * DIM + d0) = e;
            float4 rr = make_float4(e.x - xv.x, e.y - xv.y, e.z - xv.z, e.w - xv.w);
            *reinterpret_cast<float4*>(out + ROFF + (size_t)row * DIM + d0) = rr;
        }
        __syncthreads();
    }
}

// ================= fallback: R6-verified VALU path (used if ws too small) ====
#define BM 64
#define BN 64
#define DK 64
__global__ __launch_bounds__(256, 4)
void vq_argmin_kernel(const float* __restrict__ x, const float* __restrict__ embed,
                      const float* __restrict__ esq, float* __restrict__ out,
                      int N, int K) {
    __shared__ float xs[DK][BM];
    __shared__ float es[DK][BN];
    __shared__ double rv1[256], rv2[256];
    __shared__ int    ri1[256], ri2[256];
    __shared__ float  xrow[DIM];
    __shared__ int    flr[BM];
    __shared__ int    nflag;

    const int t = threadIdx.x;
    const int tx = t & 15, ty = t >> 4;
    const int row0 = blockIdx.x * BM;
    if (t == 0) nflag = 0;

    float minv[4], min2v[4]; int mini[4];
#pragma unroll
    for (int r = 0; r < 4; ++r) { minv[r] = INFINITY; min2v[r] = INFINITY; mini[r] = 0; }

    for (int jc = 0; jc < K / BN; ++jc) {
        float acc[4][4];
#pragma unroll
        for (int r = 0; r < 4; ++r)
#pragma unroll
            for (int c = 0; c < 4; ++c) acc[r][c] = 0.0f;
        for (int dc = 0; dc < DIM / DK; ++dc) {
            __syncthreads();
#pragma unroll
            for (int it = 0; it < 4; ++it) {
                int idx = t + 256 * it, r = idx & 63, kg = idx >> 6;
                float4 v = *reinterpret_cast<const float4*>(
                    x + (size_t)(row0 + r) * DIM + dc * DK + kg * 4);
                xs[kg*4+0][r] = v.x; xs[kg*4+1][r] = v.y; xs[kg*4+2][r] = v.z; xs[kg*4+3][r] = v.w;
            }
#pragma unroll
            for (int it = 0; it < 4; ++it) {
                int idx = t + 256 * it, c = idx & 63, kg = idx >> 6;
                float4 v = *reinterpret_cast<const float4*>(
                    embed + (size_t)(jc * BN + c) * DIM + dc * DK + kg * 4);
                es[kg*4+0][c] = v.x; es[kg*4+1][c] = v.y; es[kg*4+2][c] = v.z; es[kg*4+3][c] = v.w;
            }
            __syncthreads();
#pragma unroll
            for (int k = 0; k < DK; ++k) {
                float4 a = *reinterpret_cast<const float4*>(&xs[k][ty * 4]);
                float4 b = *reinterpret_cast<const float4*>(&es[k][tx * 4]);
                float arr[4] = {a.x, a.y, a.z, a.w}, bc[4] = {b.x, b.y, b.z, b.w};
#pragma unroll
                for (int r = 0; r < 4; ++r)
#pragma unroll
                    for (int c = 0; c < 4; ++c) acc[r][c] = fmaf(arr[r], bc[c], acc[r][c]);
            }
        }
        float4 eq = *reinterpret_cast<const float4*>(esq + jc * BN + tx * 4);
        float eqa[4] = {eq.x, eq.y, eq.z, eq.w};
#pragma unroll
        for (int c = 0; c < 4; ++c) {
            int j = jc * BN + tx * 4 + c;
#pragma unroll
            for (int r = 0; r < 4; ++r) {
                float s = fmaf(-2.0f, acc[r][c], eqa[c]);
                if (s < minv[r]) { min2v[r] = minv[r]; minv[r] = s; mini[r] = j; }
                else if (s < min2v[r]) { min2v[r] = s; }
            }
        }
    }
#pragma unroll
    for (int r = 0; r < 4; ++r) {
        float v1 = minv[r]; int i1 = mini[r]; float v2 = min2v[r];
#pragma unroll
        for (int m = 1; m < 16; m <<= 1) {
            float ov1 = __shfl_xor(v1, m, 64); int oi1 = __shfl_xor(i1, m, 64);
            float ov2 = __shfl_xor(v2, m, 64);
            float nv2 = fminf(fmaxf(v1, ov1), fminf(v2, ov2));
            if (ov1 < v1 || (ov1 == v1 && oi1 < i1)) { v1 = ov1; i1 = oi1; }
            v2 = nv2;
        }
        minv[r] = v1; mini[r] = i1; min2v[r] = v2;
    }
    const size_t IOFF = (size_t)N * DIM, ROFF = IOFF + (size_t)N;
#pragma unroll
    for (int r = 0; r < 4; ++r) {
        int row = row0 + ty * 4 + r, idx = mini[r];
        if (tx == 0) {
            out[IOFF + row] = (float)idx;
            if (min2v[r] - minv[r] < MARGIN_FALLBACK) { int p = atomicAdd(&nflag, 1); flr[p] = ty * 4 + r; }
        }
#pragma unroll
        for (int g = 0; g < 4; ++g) {
            int d0 = tx * 16 + g * 4;
            float4 e  = *reinterpret_cast<const float4*>(embed + (size_t)idx * DIM + d0);
            float4 xv = *reinterpret_cast<const float4*>(x + (size_t)row * DIM + d0);
            *reinterpret_cast<float4*>(out + (size_t)row * DIM + d0) = e;
            float4 rr = make_float4(e.x - xv.x, e.y - xv.y, e.z - xv.z, e.w - xv.w);
            *reinterpret_cast<float4*>(out + ROFF + (size_t)row * DIM + d0) = rr;
        }
    }
    __syncthreads();
    const int nf = nflag;
    for (int f = 0; f < nf; ++f) {
        const int row = row0 + flr[f];
        if (t < 64) {
            float4 v = *reinterpret_cast<const float4*>(x + (size_t)row * DIM + t * 4);
            xrow[t*4+0] = v.x; xrow[t*4+1] = v.y; xrow[t*4+2] = v.z; xrow[t*4+3] = v.w;
        }
        __syncthreads();
        double v1 = DBL_MAX, v2 = DBL_MAX; int i1 = 0x7fffffff, i2 = 0x7fffffff;
#pragma unroll
        for (int jj = 0; jj < 4; ++jj) {
            const int j = t * 4 + jj;
            const float* e = embed + (size_t)j * DIM;
            double xe = 0.0, ee = 0.0;
            for (int kg = 0; kg < DIM / 4; ++kg) {
                float4 ev = *reinterpret_cast<const float4*>(e + kg * 4);
                double e0 = ev.x, e1 = ev.y, e2 = ev.z, e3 = ev.w;
                xe += e0*(double)xrow[kg*4+0] + e1*(double)xrow[kg*4+1]
                    + e2*(double)xrow[kg*4+2] + e3*(double)xrow[kg*4+3];
                ee += e0*e0 + e1*e1 + e2*e2 + e3*e3;
            }
            double d = ee - 2.0 * xe;
            if (d < v1 || (d == v1 && j < i1)) { v2 = v1; i2 = i1; v1 = d; i1 = j; }
            else if (d < v2 || (d == v2 && j < i2)) { v2 = d; i2 = j; }
        }
        rv1[t] = v1; ri1[t] = i1; rv2[t] = v2; ri2[t] = i2;
        __syncthreads();
        for (int s = 128; s > 0; s >>= 1) {
            if (t < s) {
                double a1 = rv1[t], a2 = rv2[t]; int k1 = ri1[t], k2 = ri2[t];
                double b1 = rv1[t+s], b2 = rv2[t+s]; int j1 = ri1[t+s], j2 = ri2[t+s];
                double w1, w2; int m1, m2;
                bool bfirst = (b1 < a1) || (b1 == a1 && j1 < k1);
                if (bfirst) { w1 = b1; m1 = j1;
                    if (a1 < b2 || (a1 == b2 && k1 < j2)) { w2 = a1; m2 = k1; } else { w2 = b2; m2 = j2; }
                } else { w1 = a1; m1 = k1;
                    if (b1 < a2 || (b1 == a2 && j1 < k2)) { w2 = b1; m2 = j1; } else { w2 = a2; m2 = k2; }
                }
                rv1[t] = w1; ri1[t] = m1; rv2[t] = w2; ri2[t] = m2;
            }
            __syncthreads();
        }
        int idx = ri1[0];
        const double gap = rv2[0] - rv1[0];
#if PREFER_LOWER
        if (gap < EPS_TIE && ri2[0] < ri1[0]) idx = ri2[0];
#else
        if (gap < EPS_TIE && ri2[0] > ri1[0]) idx = ri2[0];
#endif
        if (t == 0) out[IOFF + row] = (float)idx;
        if (t < 64) {
            int d0 = t * 4;
            float4 e  = *reinterpret_cast<const float4*>(embed + (size_t)idx * DIM + d0);
            float4 xv = *reinterpret_cast<const float4*>(x + (size_t)row * DIM + d0);
            *reinterpret_cast<float4*>(out + (size_t)row * DIM + d0) = e;
            float4 rr = make_float4(e.x - xv.x, e.y - xv.y, e.z - xv.z, e.w - xv.w);
            *reinterpret_cast<float4*>(out + ROFF + (size_t)row * DIM + d0) = rr;
        }
        __syncthreads();
    }
}

extern "C" void kernel_launch(void* const* d_in, const int* in_sizes, int n_in,
                              void* d_out, int out_size, void* d_ws, size_t ws_size,
                              hipStream_t stream) {
    const float* x     = (const float*)d_in[0];
    const float* embed = (const float*)d_in[1];
    float* out = (float*)d_out;
    const int N = in_sizes[0] / DIM;   // 65536
    const int K = in_sizes[1] / DIM;   // 1024

    // ws: [0,4KB) esq | [4KB,+512KB) ehi | [aligned 16, 2MB) partials
    float* esq = (float*)d_ws;
    unsigned short* ehi = (unsigned short*)((char*)d_ws + 4096);
    f32x4* part = (f32x4*)((char*)d_ws + 4096 + 524288);
    const size_t need = 4096 + 524288 + (size_t)N * 2 * 16;

    esq_kernel<<<K, 64, 0, stream>>>(embed, esq);
    if (ws_size >= need) {
        efrag_kernel<<<(K / 16) * 8, 64, 0, stream>>>(embed, ehi);
        vq_fast_kernel<<<(N / 512) * 2, 512, 0, stream>>>(x, ehi, esq, part, N);
        vq_merge_kernel<<<N / 64, 256, 0, stream>>>(x, embed, part, out, N, K);
    } else {
        vq_argmin_kernel<<<N / BM, 256, 0, stream>>>(x, embed, esq, out, N, K);
    }
}